// Round 8
// baseline (273.644 us; speedup 1.0000x reference)
//
#include <hip/hip_runtime.h>
#include <cstdint>

#define N_TOT 1572864
#define KSEL 4096
#define CAP 8192
#define BINS 4096
#define SCORE_THR 0.5f
#define IOU_THR 0.1f
#define STREAM_BLOCKS 512
#define STAGE 512

__device__ inline uint64_t readlane64(uint64_t v, int lane) {
    uint32_t lo = (uint32_t)__builtin_amdgcn_readlane((int)(uint32_t)v, lane);
    uint32_t hi = (uint32_t)__builtin_amdgcn_readlane((int)(uint32_t)(v >> 32), lane);
    return ((uint64_t)hi << 32) | lo;
}

// async global->LDS, 16B per lane; LDS dest is wave-uniform base + lane*16
__device__ __forceinline__ void gload16(const void* gsrc, void* lds_uniform) {
    __builtin_amdgcn_global_load_lds(
        (const __attribute__((address_space(1))) void*)gsrc,
        (__attribute__((address_space(3))) void*)lds_uniform,
        16, 0, 0);
}

// ---------------- init: zero hist/counters/topScore ----------------
__global__ void k_init(uint32_t* hist, uint32_t* ctrs, float* topScore) {
    int i = blockIdx.x * blockDim.x + threadIdx.x;
    if (i < BINS) hist[i] = 0;
    if (i < 16) ctrs[i] = 0;
    if (i < KSEL) topScore[i] = 0.0f;
}

// ---------------- histogram over score bits (scores in (0.5,1)), float4 stream ----------------
__global__ void k_hist(const float4* __restrict__ cls4, uint32_t* __restrict__ hist) {
    int i = blockIdx.x * blockDim.x + threadIdx.x;
    int stride = gridDim.x * blockDim.x;
    for (; i < N_TOT / 2; i += stride) {
        float4 c = cls4[i];
        if (c.y > SCORE_THR) {
            uint32_t bin = (__float_as_uint(c.y) - 0x3F000000u) >> 11;
            if (bin >= BINS) bin = BINS - 1;
            atomicAdd(&hist[bin], 1u);
        }
        if (c.w > SCORE_THR) {
            uint32_t bin = (__float_as_uint(c.w) - 0x3F000000u) >> 11;
            if (bin >= BINS) bin = BINS - 1;
            atomicAdd(&hist[bin], 1u);
        }
    }
}

// ---------------- find cutoff bin T: largest b with suffix(b) >= K ----------------
__global__ __launch_bounds__(1024) void k_thresh(const uint32_t* __restrict__ hist,
                                                 uint32_t* __restrict__ ctrs) {
    __shared__ uint32_t s_suf[1024];
    int t = threadIdx.x;
    uint32_t l0 = hist[t*4+0], l1 = hist[t*4+1], l2 = hist[t*4+2], l3 = hist[t*4+3];
    s_suf[t] = l0 + l1 + l2 + l3;
    __syncthreads();
    for (int off = 1; off < 1024; off <<= 1) {
        uint32_t v = (t + off < 1024) ? s_suf[t + off] : 0u;
        __syncthreads();
        s_suf[t] += v;
        __syncthreads();
    }
    uint32_t snext = (t < 1023) ? s_suf[t + 1] : 0u;
    uint32_t suf3 = snext + l3;
    uint32_t suf2 = suf3 + l2;
    uint32_t suf1 = suf2 + l1;
    uint32_t suf0 = suf1 + l0;
    uint32_t sufs[5] = {suf0, suf1, suf2, suf3, snext};
    #pragma unroll
    for (int q = 0; q < 4; q++) {
        if (sufs[q] >= KSEL && sufs[q+1] < KSEL) ctrs[1] = (uint32_t)(t*4 + q);
    }
    if (t == 0 && s_suf[0] < KSEL) ctrs[1] = 0;  // fewer than K candidates
}

// ---------------- gather candidates (bin >= T) via LDS staging; 1 global atomic/block ----------------
__global__ void k_gather(const float4* __restrict__ cls4, uint32_t* __restrict__ ctrs,
                         uint64_t* __restrict__ keys) {
    __shared__ uint32_t s_cnt;
    __shared__ uint32_t s_base;
    __shared__ uint64_t s_stage[STAGE];
    if (threadIdx.x == 0) s_cnt = 0;
    __syncthreads();

    uint32_t T = ctrs[1];
    uint32_t basebits = 0x3F000000u + (T << 11);
    int i = blockIdx.x * blockDim.x + threadIdx.x;
    int stride = gridDim.x * blockDim.x;
    for (; i < N_TOT / 2; i += stride) {
        float4 c = cls4[i];
        #pragma unroll
        for (int h = 0; h < 2; h++) {
            float s = h ? c.w : c.y;
            uint32_t idx = 2u * (uint32_t)i + (uint32_t)h;
            if (s > SCORE_THR) {
                uint32_t b = __float_as_uint(s);
                if (b >= basebits) {
                    uint64_t key = ((uint64_t)b << 32) | (uint32_t)(~idx);
                    uint32_t p = atomicAdd(&s_cnt, 1u);
                    if (p < STAGE) s_stage[p] = key;
                    else {  // overflow: rare fallback, correctness-preserving
                        uint32_t g = atomicAdd(&ctrs[0], 1u);
                        if (g < CAP) keys[g] = key;
                    }
                }
            }
        }
    }
    __syncthreads();
    uint32_t n = s_cnt < STAGE ? s_cnt : STAGE;
    if (threadIdx.x == 0 && n > 0) s_base = atomicAdd(&ctrs[0], n);
    __syncthreads();
    for (uint32_t q = threadIdx.x; q < n; q += blockDim.x) {
        uint32_t g = s_base + q;
        if (g < CAP) keys[g] = s_stage[q];
    }
}

// ---------------- exact rank sort + fused decode (numpy f32 rounding, no FMA) ----------------
__global__ void k_rankdec(const uint64_t* __restrict__ keys, const uint32_t* __restrict__ ctrs,
                          const float* __restrict__ anchors, const float* __restrict__ reg,
                          float* __restrict__ topScore, float* __restrict__ boxes,
                          float* __restrict__ areas) {
    __shared__ uint64_t s_keys[256];
    uint32_t M = ctrs[0]; if (M > CAP) M = CAP;
    int j = blockIdx.x * blockDim.x + threadIdx.x;
    uint64_t myKey = (j < (int)M) ? keys[j] : 0ull;
    uint32_t rank = 0;
    for (uint32_t base = 0; base < M; base += 256) {
        uint32_t idx = base + threadIdx.x;
        s_keys[threadIdx.x] = (idx < M) ? keys[idx] : 0ull;
        __syncthreads();
        uint32_t lim = min(256u, M - base);
        for (uint32_t q = 0; q < lim; q++)
            rank += (s_keys[q] > myKey) ? 1u : 0u;
        __syncthreads();
    }
    if (j < (int)M && rank < KSEL) {
        uint32_t srcIdx = ~((uint32_t)(myKey & 0xFFFFFFFFull));
        topScore[rank] = __uint_as_float((uint32_t)(myKey >> 32));
        float4 a = *reinterpret_cast<const float4*>(&anchors[(size_t)srcIdx * 4]);
        float4 dd = *reinterpret_cast<const float4*>(&reg[(size_t)srcIdx * 4]);
        float d0 = __fmul_rn(dd.x, 0.1f);
        float d1 = __fmul_rn(dd.y, 0.1f);
        float d2 = __fmul_rn(dd.z, 0.2f);
        float d3 = __fmul_rn(dd.w, 0.2f);
        float w  = __fsub_rn(a.z, a.x);
        float h  = __fsub_rn(a.w, a.y);
        float cx = __fadd_rn(a.x, __fmul_rn(0.5f, w));
        float cy = __fadd_rn(a.y, __fmul_rn(0.5f, h));
        float pcx = __fadd_rn(cx, __fmul_rn(d0, w));
        float pcy = __fadd_rn(cy, __fmul_rn(d1, h));
        float pw = __fmul_rn((float)exp((double)d2), w);
        float ph = __fmul_rn((float)exp((double)d3), h);
        float x0 = __fsub_rn(pcx, __fmul_rn(0.5f, pw));
        float y0 = __fsub_rn(pcy, __fmul_rn(0.5f, ph));
        float x1 = __fadd_rn(pcx, __fmul_rn(0.5f, pw));
        float y1 = __fadd_rn(pcy, __fmul_rn(0.5f, ph));
        x0 = fminf(fmaxf(x0, 0.0f), 1024.0f);
        y0 = fminf(fmaxf(y0, 0.0f), 1024.0f);
        x1 = fminf(fmaxf(x1, 0.0f), 1024.0f);
        y1 = fminf(fmaxf(y1, 0.0f), 1024.0f);
        *reinterpret_cast<float4*>(&boxes[(size_t)rank * 4]) = make_float4(x0, y0, x1, y1);
        areas[rank] = __fmul_rn(__fsub_rn(x1, x0), __fsub_rn(y1, y0));
    }
}

// ---------------- pairwise suppression bitmask; lower-triangle blocks write 0 ----------------
__global__ void k_mask(const float* __restrict__ boxes, const float* __restrict__ areas,
                       unsigned long long* __restrict__ rowmask) {
    int bi = blockIdx.y, bj = blockIdx.x;
    int t = threadIdx.x;
    if (bj < bi) {  // zero-fill so reduce can AND rows unguarded
        rowmask[(size_t)(bi * 64 + t) * 64 + bj] = 0ull;
        return;
    }
    __shared__ float s_box[64][4];
    __shared__ float s_area[64];
    int r0 = bi * 64 + t;
    s_box[t][0] = boxes[r0 * 4 + 0];
    s_box[t][1] = boxes[r0 * 4 + 1];
    s_box[t][2] = boxes[r0 * 4 + 2];
    s_box[t][3] = boxes[r0 * 4 + 3];
    s_area[t] = areas[r0];
    __syncthreads();
    int j = bj * 64 + t;
    float jx0 = boxes[j * 4 + 0], jy0 = boxes[j * 4 + 1], jx1 = boxes[j * 4 + 2], jy1 = boxes[j * 4 + 3];
    float ja = areas[j];
    unsigned long long myword = 0ull;
    #pragma unroll 4
    for (int r = 0; r < 64; r++) {
        int i = bi * 64 + r;
        float w = __fsub_rn(fminf(s_box[r][2], jx1), fmaxf(s_box[r][0], jx0));
        float h = __fsub_rn(fminf(s_box[r][3], jy1), fmaxf(s_box[r][1], jy0));
        w = fmaxf(w, 0.0f); h = fmaxf(h, 0.0f);
        float inter = __fmul_rn(w, h);
        float denom = __fadd_rn(__fsub_rn(__fadd_rn(s_area[r], ja), inter), 1e-8f);
        float iou = __fdiv_rn(inter, denom);
        bool sup = (iou > IOU_THR) && (j > i);
        unsigned long long b = __ballot(sup);
        if (t == r) myword = b;
    }
    rowmask[(size_t)(bi * 64 + t) * 64 + bj] = myword;
}

// ---------------- block-diagonal greedy NMS reduce: 2-wave LDS producer/consumer ----------------
// Wave 1 stages block b+1's 32KB (64 rows x 512B) into an LDS slot via
// global_load_lds (no VGPR staging -> compiler cannot sink the pipeline, R7's
// failure mode). Wave 0 computes block b from the other slot. Barrier ping-pong.
__global__ __launch_bounds__(128, 1) void k_reduce(const float* __restrict__ topScore,
                         const unsigned long long* __restrict__ rowmask,
                         const float* __restrict__ boxes,
                         const int* __restrict__ Hp, const int* __restrict__ Wp,
                         float* __restrict__ out) {
    __shared__ uint64_t lds[2][4096];   // 2 slots x (64 rows x 64 words)
    int tid = threadIdx.x;
    int wid = tid >> 6;   // 0 = compute, 1 = loader
    int l = tid & 63;

    const char* rmbytes = (const char*)rowmask;

    // loader: stage block 0 into slot 0
    if (wid == 1) {
        #pragma unroll
        for (int k = 0; k < 32; k++) {
            gload16(rmbytes + (size_t)0 * 32768 + k * 1024 + l * 16,
                    (char*)&lds[0][0] + k * 1024);
        }
    }

    // compute wave: build keep bits while block 0 is in flight
    uint64_t keep = 0ull;
    if (wid == 0) {
        #pragma unroll
        for (int c = 0; c < 64; c += 4) {
            float4 s4 = *reinterpret_cast<const float4*>(&topScore[l * 64 + c]);
            keep |= ((uint64_t)(s4.x > 0.0f) << (c + 0))
                 |  ((uint64_t)(s4.y > 0.0f) << (c + 1))
                 |  ((uint64_t)(s4.z > 0.0f) << (c + 2))
                 |  ((uint64_t)(s4.w > 0.0f) << (c + 3));
        }
    }
    __syncthreads();

    for (int b = 0; b < 64; b++) {
        if (wid == 1) {
            if (b + 1 < 64) {
                int s = (b + 1) & 1;
                #pragma unroll
                for (int k = 0; k < 32; k++) {
                    gload16(rmbytes + (size_t)(b + 1) * 32768 + k * 1024 + l * 16,
                            (char*)&lds[s][0] + k * 1024);
                }
            }
        } else {
            const uint64_t* slot = &lds[b & 1][0];
            // diag: lane i holds row (b*64+i)'s word b
            uint64_t diag = slot[l * 64 + b];
            // phase 1: scalar within-block suppression (acting set == final alive set)
            uint32_t klo = (uint32_t)__builtin_amdgcn_readlane((int)(uint32_t)keep, b);
            uint32_t khi = (uint32_t)__builtin_amdgcn_readlane((int)(uint32_t)(keep >> 32), b);
            uint64_t kw = ((uint64_t)khi << 32) | klo;
            uint64_t rem = kw;
            while (rem) {
                int i = __builtin_ctzll(rem);
                rem &= rem - 1;
                uint64_t row = readlane64(diag, i);
                kw &= ~row;
                rem &= ~row;
            }
            // phase 2: branchless masked OR of all 64 rows (word l) from LDS
            uint64_t acc = 0ull;
            #pragma unroll 8
            for (int r = 0; r < 64; r++) {
                uint64_t m = (uint64_t)0 - ((kw >> r) & 1ull);
                acc |= slot[r * 64 + l] & m;
            }
            keep &= ~acc;   // lower-tri words are zero rows; lane b reproduces kw
        }
        __syncthreads();
    }

    // fused output: wave 0, lane l owns rows [l*64, l*64+64)
    if (wid == 0) {
        float sx = (float)((double)Wp[0] / 1024.0);
        float sy = (float)((double)Hp[0] / 1024.0);
        for (int c = 0; c < 64; c++) {
            int k = l * 64 + c;
            float f = ((keep >> c) & 1ull) ? 1.0f : 0.0f;
            float4 bx = *reinterpret_cast<const float4*>(&boxes[(size_t)k * 4]);
            out[k * 5 + 0] = __fmul_rn(__fmul_rn(bx.x, sx), f);
            out[k * 5 + 1] = __fmul_rn(__fmul_rn(bx.y, sy), f);
            out[k * 5 + 2] = __fmul_rn(__fmul_rn(bx.z, sx), f);
            out[k * 5 + 3] = __fmul_rn(__fmul_rn(bx.w, sy), f);
            out[k * 5 + 4] = __fmul_rn(topScore[k], f);
        }
    }
}

extern "C" void kernel_launch(void* const* d_in, const int* in_sizes, int n_in,
                              void* d_out, int out_size, void* d_ws, size_t ws_size,
                              hipStream_t stream) {
    (void)in_sizes; (void)n_in; (void)out_size; (void)ws_size;
    const float4* cls4   = (const float4*)d_in[0];
    const float* reg     = (const float*)d_in[1];
    const float* anchors = (const float*)d_in[2];
    const int* Hp        = (const int*)d_in[3];
    const int* Wp        = (const int*)d_in[4];
    float* out = (float*)d_out;

    char* ws = (char*)d_ws;
    size_t off = 0;
    auto alloc = [&](size_t bytes) {
        char* p = ws + off;
        off = (off + bytes + 255) & ~(size_t)255;
        return p;
    };
    uint32_t* hist   = (uint32_t*)alloc(BINS * 4);
    uint32_t* ctrs   = (uint32_t*)alloc(64);
    uint64_t* keys   = (uint64_t*)alloc((size_t)CAP * 8);
    float* topScore  = (float*)alloc(KSEL * 4);
    float* boxes     = (float*)alloc(KSEL * 4 * 4);
    float* areas     = (float*)alloc(KSEL * 4);
    unsigned long long* rowmask = (unsigned long long*)alloc((size_t)KSEL * 64 * 8);

    k_init<<<16, 256, 0, stream>>>(hist, ctrs, topScore);
    k_hist<<<STREAM_BLOCKS, 256, 0, stream>>>(cls4, hist);
    k_thresh<<<1, 1024, 0, stream>>>(hist, ctrs);
    k_gather<<<STREAM_BLOCKS, 256, 0, stream>>>(cls4, ctrs, keys);
    k_rankdec<<<CAP / 256, 256, 0, stream>>>(keys, ctrs, anchors, reg, topScore, boxes, areas);
    dim3 mg(64, 64);
    k_mask<<<mg, 64, 0, stream>>>(boxes, areas, rowmask);
    k_reduce<<<1, 128, 0, stream>>>(topScore, rowmask, boxes, Hp, Wp, out);
}

// Round 9
// 242.891 us; speedup vs baseline: 1.1266x; 1.1266x over previous
//
#include <hip/hip_runtime.h>
#include <cstdint>

#define N_TOT 1572864
#define KSEL 4096
#define CAP 8192
#define BINS 4096
#define SCORE_THR 0.5f
#define IOU_THR 0.1f
#define STREAM_BLOCKS 512
#define STAGE 512

__device__ inline uint64_t readlane64(uint64_t v, int lane) {
    uint32_t lo = (uint32_t)__builtin_amdgcn_readlane((int)(uint32_t)v, lane);
    uint32_t hi = (uint32_t)__builtin_amdgcn_readlane((int)(uint32_t)(v >> 32), lane);
    return ((uint64_t)hi << 32) | lo;
}

// ---------------- init: zero hist/counters/topScore ----------------
__global__ void k_init(uint32_t* hist, uint32_t* ctrs, float* topScore) {
    int i = blockIdx.x * blockDim.x + threadIdx.x;
    if (i < BINS) hist[i] = 0;
    if (i < 16) ctrs[i] = 0;
    if (i < KSEL) topScore[i] = 0.0f;
}

// ---------------- histogram over score bits (scores in (0.5,1)), float4 stream ----------------
__global__ void k_hist(const float4* __restrict__ cls4, uint32_t* __restrict__ hist) {
    int i = blockIdx.x * blockDim.x + threadIdx.x;
    int stride = gridDim.x * blockDim.x;
    for (; i < N_TOT / 2; i += stride) {
        float4 c = cls4[i];
        if (c.y > SCORE_THR) {
            uint32_t bin = (__float_as_uint(c.y) - 0x3F000000u) >> 11;
            if (bin >= BINS) bin = BINS - 1;
            atomicAdd(&hist[bin], 1u);
        }
        if (c.w > SCORE_THR) {
            uint32_t bin = (__float_as_uint(c.w) - 0x3F000000u) >> 11;
            if (bin >= BINS) bin = BINS - 1;
            atomicAdd(&hist[bin], 1u);
        }
    }
}

// ---------------- find cutoff bin T: largest b with suffix(b) >= K ----------------
__global__ __launch_bounds__(1024) void k_thresh(const uint32_t* __restrict__ hist,
                                                 uint32_t* __restrict__ ctrs) {
    __shared__ uint32_t s_suf[1024];
    int t = threadIdx.x;
    uint32_t l0 = hist[t*4+0], l1 = hist[t*4+1], l2 = hist[t*4+2], l3 = hist[t*4+3];
    s_suf[t] = l0 + l1 + l2 + l3;
    __syncthreads();
    for (int off = 1; off < 1024; off <<= 1) {
        uint32_t v = (t + off < 1024) ? s_suf[t + off] : 0u;
        __syncthreads();
        s_suf[t] += v;
        __syncthreads();
    }
    uint32_t snext = (t < 1023) ? s_suf[t + 1] : 0u;
    uint32_t suf3 = snext + l3;
    uint32_t suf2 = suf3 + l2;
    uint32_t suf1 = suf2 + l1;
    uint32_t suf0 = suf1 + l0;
    uint32_t sufs[5] = {suf0, suf1, suf2, suf3, snext};
    #pragma unroll
    for (int q = 0; q < 4; q++) {
        if (sufs[q] >= KSEL && sufs[q+1] < KSEL) ctrs[1] = (uint32_t)(t*4 + q);
    }
    if (t == 0 && s_suf[0] < KSEL) ctrs[1] = 0;  // fewer than K candidates
}

// ---------------- gather candidates (bin >= T) via LDS staging; 1 global atomic/block ----------------
__global__ void k_gather(const float4* __restrict__ cls4, uint32_t* __restrict__ ctrs,
                         uint64_t* __restrict__ keys) {
    __shared__ uint32_t s_cnt;
    __shared__ uint32_t s_base;
    __shared__ uint64_t s_stage[STAGE];
    if (threadIdx.x == 0) s_cnt = 0;
    __syncthreads();

    uint32_t T = ctrs[1];
    uint32_t basebits = 0x3F000000u + (T << 11);
    int i = blockIdx.x * blockDim.x + threadIdx.x;
    int stride = gridDim.x * blockDim.x;
    for (; i < N_TOT / 2; i += stride) {
        float4 c = cls4[i];
        #pragma unroll
        for (int h = 0; h < 2; h++) {
            float s = h ? c.w : c.y;
            uint32_t idx = 2u * (uint32_t)i + (uint32_t)h;
            if (s > SCORE_THR) {
                uint32_t b = __float_as_uint(s);
                if (b >= basebits) {
                    uint64_t key = ((uint64_t)b << 32) | (uint32_t)(~idx);
                    uint32_t p = atomicAdd(&s_cnt, 1u);
                    if (p < STAGE) s_stage[p] = key;
                    else {  // overflow: rare fallback, correctness-preserving
                        uint32_t g = atomicAdd(&ctrs[0], 1u);
                        if (g < CAP) keys[g] = key;
                    }
                }
            }
        }
    }
    __syncthreads();
    uint32_t n = s_cnt < STAGE ? s_cnt : STAGE;
    if (threadIdx.x == 0 && n > 0) s_base = atomicAdd(&ctrs[0], n);
    __syncthreads();
    for (uint32_t q = threadIdx.x; q < n; q += blockDim.x) {
        uint32_t g = s_base + q;
        if (g < CAP) keys[g] = s_stage[q];
    }
}

// ---------------- exact rank sort + fused decode (numpy f32 rounding, no FMA) ----------------
__global__ void k_rankdec(const uint64_t* __restrict__ keys, const uint32_t* __restrict__ ctrs,
                          const float* __restrict__ anchors, const float* __restrict__ reg,
                          float* __restrict__ topScore, float* __restrict__ boxes,
                          float* __restrict__ areas) {
    __shared__ uint64_t s_keys[256];
    uint32_t M = ctrs[0]; if (M > CAP) M = CAP;
    int j = blockIdx.x * blockDim.x + threadIdx.x;
    uint64_t myKey = (j < (int)M) ? keys[j] : 0ull;
    uint32_t rank = 0;
    for (uint32_t base = 0; base < M; base += 256) {
        uint32_t idx = base + threadIdx.x;
        s_keys[threadIdx.x] = (idx < M) ? keys[idx] : 0ull;
        __syncthreads();
        uint32_t lim = min(256u, M - base);
        for (uint32_t q = 0; q < lim; q++)
            rank += (s_keys[q] > myKey) ? 1u : 0u;
        __syncthreads();
    }
    if (j < (int)M && rank < KSEL) {
        uint32_t srcIdx = ~((uint32_t)(myKey & 0xFFFFFFFFull));
        topScore[rank] = __uint_as_float((uint32_t)(myKey >> 32));
        float4 a = *reinterpret_cast<const float4*>(&anchors[(size_t)srcIdx * 4]);
        float4 dd = *reinterpret_cast<const float4*>(&reg[(size_t)srcIdx * 4]);
        float d0 = __fmul_rn(dd.x, 0.1f);
        float d1 = __fmul_rn(dd.y, 0.1f);
        float d2 = __fmul_rn(dd.z, 0.2f);
        float d3 = __fmul_rn(dd.w, 0.2f);
        float w  = __fsub_rn(a.z, a.x);
        float h  = __fsub_rn(a.w, a.y);
        float cx = __fadd_rn(a.x, __fmul_rn(0.5f, w));
        float cy = __fadd_rn(a.y, __fmul_rn(0.5f, h));
        float pcx = __fadd_rn(cx, __fmul_rn(d0, w));
        float pcy = __fadd_rn(cy, __fmul_rn(d1, h));
        float pw = __fmul_rn((float)exp((double)d2), w);
        float ph = __fmul_rn((float)exp((double)d3), h);
        float x0 = __fsub_rn(pcx, __fmul_rn(0.5f, pw));
        float y0 = __fsub_rn(pcy, __fmul_rn(0.5f, ph));
        float x1 = __fadd_rn(pcx, __fmul_rn(0.5f, pw));
        float y1 = __fadd_rn(pcy, __fmul_rn(0.5f, ph));
        x0 = fminf(fmaxf(x0, 0.0f), 1024.0f);
        y0 = fminf(fmaxf(y0, 0.0f), 1024.0f);
        x1 = fminf(fmaxf(x1, 0.0f), 1024.0f);
        y1 = fminf(fmaxf(y1, 0.0f), 1024.0f);
        *reinterpret_cast<float4*>(&boxes[(size_t)rank * 4]) = make_float4(x0, y0, x1, y1);
        areas[rank] = __fmul_rn(__fsub_rn(x1, x0), __fsub_rn(y1, y0));
    }
}

// ---------------- pairwise suppression bitmask; lower-triangle blocks write 0 ----------------
__global__ void k_mask(const float* __restrict__ boxes, const float* __restrict__ areas,
                       unsigned long long* __restrict__ rowmask) {
    int bi = blockIdx.y, bj = blockIdx.x;
    int t = threadIdx.x;
    if (bj < bi) {  // zero-fill so reduce can AND rows unguarded
        rowmask[(size_t)(bi * 64 + t) * 64 + bj] = 0ull;
        return;
    }
    __shared__ float s_box[64][4];
    __shared__ float s_area[64];
    int r0 = bi * 64 + t;
    s_box[t][0] = boxes[r0 * 4 + 0];
    s_box[t][1] = boxes[r0 * 4 + 1];
    s_box[t][2] = boxes[r0 * 4 + 2];
    s_box[t][3] = boxes[r0 * 4 + 3];
    s_area[t] = areas[r0];
    __syncthreads();
    int j = bj * 64 + t;
    float jx0 = boxes[j * 4 + 0], jy0 = boxes[j * 4 + 1], jx1 = boxes[j * 4 + 2], jy1 = boxes[j * 4 + 3];
    float ja = areas[j];
    unsigned long long myword = 0ull;
    #pragma unroll 4
    for (int r = 0; r < 64; r++) {
        int i = bi * 64 + r;
        float w = __fsub_rn(fminf(s_box[r][2], jx1), fmaxf(s_box[r][0], jx0));
        float h = __fsub_rn(fminf(s_box[r][3], jy1), fmaxf(s_box[r][1], jy0));
        w = fmaxf(w, 0.0f); h = fmaxf(h, 0.0f);
        float inter = __fmul_rn(w, h);
        float denom = __fadd_rn(__fsub_rn(__fadd_rn(s_area[r], ja), inter), 1e-8f);
        float iou = __fdiv_rn(inter, denom);
        bool sup = (iou > IOU_THR) && (j > i);
        unsigned long long b = __ballot(sup);
        if (t == r) myword = b;
    }
    rowmask[(size_t)(bi * 64 + t) * 64 + bj] = myword;
}

// ---------------- block-diagonal greedy NMS reduce + fused output ----------------
// 1 wave; lane w owns keep word w. Phase-2 rows for block b are indexed by
// keep[b] BEFORE phase-1 (a superset of the final alive set), so up to 16 row
// loads are issued speculatively BEFORE the serial phase-1 chain; latency hides
// under it. sched_barrier(0) pins the loads (R7: allocator sank buffered
// loads); final alive mask applied as register AND-OR. Overflow rows (>16
// alive-before) use rare post-phase-1 conditional rounds.
#define EXTRACT(s) \
    idx##s = rr ? (uint32_t)__builtin_ctzll(rr) : 63u; rr &= rr - 1;
#define LOADV(s) \
    v##s = base[(size_t)idx##s * 64];
#define ORV(s) \
    acc |= v##s & ((uint64_t)0 - ((kw >> idx##s) & 1ull));

__global__ __launch_bounds__(64, 1) void k_reduce(const float* __restrict__ topScore,
                         const unsigned long long* __restrict__ rowmask,
                         const float* __restrict__ boxes,
                         const int* __restrict__ Hp, const int* __restrict__ Wp,
                         float* __restrict__ out) {
    int w = threadIdx.x;  // 0..63
    uint64_t keep = 0ull;
    #pragma unroll
    for (int c = 0; c < 64; c += 4) {
        float4 s4 = *reinterpret_cast<const float4*>(&topScore[w * 64 + c]);
        keep |= ((uint64_t)(s4.x > 0.0f) << (c + 0))
             |  ((uint64_t)(s4.y > 0.0f) << (c + 1))
             |  ((uint64_t)(s4.z > 0.0f) << (c + 2))
             |  ((uint64_t)(s4.w > 0.0f) << (c + 3));
    }

    // diag prefetch 2 blocks ahead: lane i holds row (b*64+i)'s word b
    uint64_t dg0 = rowmask[(size_t)(0 * 64 + w) * 64 + 0];
    uint64_t dg1 = rowmask[(size_t)(1 * 64 + w) * 64 + 1];

    for (int b = 0; b < 64; b++) {
        const unsigned long long* base = rowmask + (size_t)(b * 64) * 64 + w;

        // ---- speculative phase-2 load issue (indices from keep word b, pre-phase-1)
        uint64_t kb = readlane64(keep, b);
        uint64_t rr = kb;
        uint32_t idx0, idx1, idx2, idx3, idx4, idx5, idx6, idx7;
        uint32_t idx8, idx9, idx10, idx11, idx12, idx13, idx14, idx15;
        EXTRACT(0) EXTRACT(1) EXTRACT(2) EXTRACT(3)
        EXTRACT(4) EXTRACT(5) EXTRACT(6) EXTRACT(7)
        EXTRACT(8) EXTRACT(9) EXTRACT(10) EXTRACT(11)
        EXTRACT(12) EXTRACT(13) EXTRACT(14) EXTRACT(15)
        uint64_t v0, v1, v2, v3, v4, v5, v6, v7;
        uint64_t v8, v9, v10, v11, v12, v13, v14, v15;
        LOADV(0) LOADV(1) LOADV(2) LOADV(3)
        LOADV(4) LOADV(5) LOADV(6) LOADV(7)
        LOADV(8) LOADV(9) LOADV(10) LOADV(11)
        LOADV(12) LOADV(13) LOADV(14) LOADV(15)
        __builtin_amdgcn_sched_barrier(0);   // loads must not sink below here

        uint64_t diag = dg0;
        dg0 = dg1;
        int nb = (b + 2 < 64) ? (b + 2) : 63;
        dg1 = rowmask[(size_t)(nb * 64 + w) * 64 + nb];

        // ---- phase 1: scalar within-block suppression (runs under load shadow)
        uint64_t kw = kb;
        uint64_t rem = kw;
        while (rem) {
            int i = __builtin_ctzll(rem);
            rem &= rem - 1;
            uint64_t row = readlane64(diag, i);
            kw &= ~row;
            rem &= ~row;
        }

        // ---- phase 2: masked OR of the 16 speculative rows (compiler waitcnts)
        uint64_t acc = 0ull;
        ORV(0) ORV(1) ORV(2) ORV(3)
        ORV(4) ORV(5) ORV(6) ORV(7)
        ORV(8) ORV(9) ORV(10) ORV(11)
        ORV(12) ORV(13) ORV(14) ORV(15)

        // ---- overflow rounds: alive-before rows beyond the first 16 (rare)
        uint64_t rem2 = rr & kw;
        while (rem2) {
            int i0 = __builtin_ctzll(rem2); uint64_t r = rem2 & (rem2 - 1);
            int i1 = r ? __builtin_ctzll(r) : i0; r = r ? (r & (r - 1)) : r;
            int i2 = r ? __builtin_ctzll(r) : i0; r = r ? (r & (r - 1)) : r;
            int i3 = r ? __builtin_ctzll(r) : i0; r = r ? (r & (r - 1)) : r;
            int i4 = r ? __builtin_ctzll(r) : i0; r = r ? (r & (r - 1)) : r;
            int i5 = r ? __builtin_ctzll(r) : i0; r = r ? (r & (r - 1)) : r;
            int i6 = r ? __builtin_ctzll(r) : i0; r = r ? (r & (r - 1)) : r;
            int i7 = r ? __builtin_ctzll(r) : i0; r = r ? (r & (r - 1)) : r;
            rem2 = r;
            uint64_t r0 = base[(size_t)i0 * 64];
            uint64_t r1 = base[(size_t)i1 * 64];
            uint64_t r2 = base[(size_t)i2 * 64];
            uint64_t r3 = base[(size_t)i3 * 64];
            uint64_t r4 = base[(size_t)i4 * 64];
            uint64_t r5 = base[(size_t)i5 * 64];
            uint64_t r6 = base[(size_t)i6 * 64];
            uint64_t r7 = base[(size_t)i7 * 64];
            acc |= (r0 | r1) | (r2 | r3) | ((r4 | r5) | (r6 | r7));
        }

        keep &= ~acc;   // lower-tri words are zero rows; lane b reproduces kw
    }

    // fused output: lane w owns rows [w*64, w*64+64)
    float sx = (float)((double)Wp[0] / 1024.0);
    float sy = (float)((double)Hp[0] / 1024.0);
    for (int c = 0; c < 64; c++) {
        int k = w * 64 + c;
        float f = ((keep >> c) & 1ull) ? 1.0f : 0.0f;
        float4 bx = *reinterpret_cast<const float4*>(&boxes[(size_t)k * 4]);
        out[k * 5 + 0] = __fmul_rn(__fmul_rn(bx.x, sx), f);
        out[k * 5 + 1] = __fmul_rn(__fmul_rn(bx.y, sy), f);
        out[k * 5 + 2] = __fmul_rn(__fmul_rn(bx.z, sx), f);
        out[k * 5 + 3] = __fmul_rn(__fmul_rn(bx.w, sy), f);
        out[k * 5 + 4] = __fmul_rn(topScore[k], f);
    }
}

extern "C" void kernel_launch(void* const* d_in, const int* in_sizes, int n_in,
                              void* d_out, int out_size, void* d_ws, size_t ws_size,
                              hipStream_t stream) {
    (void)in_sizes; (void)n_in; (void)out_size; (void)ws_size;
    const float4* cls4   = (const float4*)d_in[0];
    const float* reg     = (const float*)d_in[1];
    const float* anchors = (const float*)d_in[2];
    const int* Hp        = (const int*)d_in[3];
    const int* Wp        = (const int*)d_in[4];
    float* out = (float*)d_out;

    char* ws = (char*)d_ws;
    size_t off = 0;
    auto alloc = [&](size_t bytes) {
        char* p = ws + off;
        off = (off + bytes + 255) & ~(size_t)255;
        return p;
    };
    uint32_t* hist   = (uint32_t*)alloc(BINS * 4);
    uint32_t* ctrs   = (uint32_t*)alloc(64);
    uint64_t* keys   = (uint64_t*)alloc((size_t)CAP * 8);
    float* topScore  = (float*)alloc(KSEL * 4);
    float* boxes     = (float*)alloc(KSEL * 4 * 4);
    float* areas     = (float*)alloc(KSEL * 4);
    unsigned long long* rowmask = (unsigned long long*)alloc((size_t)KSEL * 64 * 8);

    k_init<<<16, 256, 0, stream>>>(hist, ctrs, topScore);
    k_hist<<<STREAM_BLOCKS, 256, 0, stream>>>(cls4, hist);
    k_thresh<<<1, 1024, 0, stream>>>(hist, ctrs);
    k_gather<<<STREAM_BLOCKS, 256, 0, stream>>>(cls4, ctrs, keys);
    k_rankdec<<<CAP / 256, 256, 0, stream>>>(keys, ctrs, anchors, reg, topScore, boxes, areas);
    dim3 mg(64, 64);
    k_mask<<<mg, 64, 0, stream>>>(boxes, areas, rowmask);
    k_reduce<<<1, 64, 0, stream>>>(topScore, rowmask, boxes, Hp, Wp, out);
}